// Round 7
// baseline (484.728 us; speedup 1.0000x reference)
//
#include <hip/hip_runtime.h>
#include <math.h>

#define B_    4
#define CDIM  512
#define HEADS 8
#define HD    64
#define NN    4096
#define QSZ   ((size_t)B_*HEADS*NN*HD)   // 8388608 elements
// q scale folded with log2(e): 0.125 * 1.4426950408889634
#define SCALE_Q 0.18033688011112042f

typedef __attribute__((ext_vector_type(8))) short short8;   // 8 bf16
typedef __attribute__((ext_vector_type(4))) float f32x4;
union U4S8 { uint4 u; short8 s; };

// RNE fp32 -> bf16
__device__ inline unsigned pk(float a, float b) {
    unsigned ua = __float_as_uint(a), ub = __float_as_uint(b);
    ua += 0x7FFFu + ((ua >> 16) & 1u);
    ub += 0x7FFFu + ((ub >> 16) & 1u);
    return (ua >> 16) | (ub & 0xFFFF0000u);
}
__device__ inline unsigned short bf16_1(float a) {
    unsigned ua = __float_as_uint(a);
    ua += 0x7FFFu + ((ua >> 16) & 1u);
    return (unsigned short)(ua >> 16);
}
// cheap round-half-up pack (positive inputs): 2 adds + 1 v_perm
__device__ inline unsigned pkru(float a, float b) {
    unsigned ua = __float_as_uint(a) + 0x8000u;
    unsigned ub = __float_as_uint(b) + 0x8000u;
    return __builtin_amdgcn_perm(ub, ua, 0x07060302);  // [hi16(ua) | hi16(ub)<<16]
}

__device__ inline void load_lds16(const unsigned short* g, unsigned short* l) {
    __builtin_amdgcn_global_load_lds(
        (const __attribute__((address_space(1))) unsigned int*)g,
        (__attribute__((address_space(3))) unsigned int*)l, 16, 0, 0);
}

// ------------------------------------------------------- weights -> bf16
__global__ void conv_w_kernel(const float* __restrict__ wq, const float* __restrict__ wp,
                              unsigned short* __restrict__ wqb, unsigned short* __restrict__ wpb) {
    int id = blockIdx.x * 256 + threadIdx.x;
    const float* src; unsigned short* dst; size_t off; float sc = 1.0f;
    if (id < 98304) { src = wq; dst = wqb; off = (size_t)id * 8; if (off < 262144) sc = SCALE_Q; }
    else            { src = wp; dst = wpb; off = (size_t)(id - 98304) * 8; }
    float4 a = *(const float4*)(src + off);
    float4 b = *(const float4*)(src + off + 4);
    uint4 u;
    u.x = pk(a.x * sc, a.y * sc); u.y = pk(a.z * sc, a.w * sc);
    u.z = pk(b.x * sc, b.y * sc); u.w = pk(b.z * sc, b.w * sc);
    *(uint4*)(dst + off) = u;
}

// ------------------------------------------------------- rope tables [j][n]
__global__ void rope_table_kernel(float* __restrict__ ct, float* __restrict__ st) {
    int id = blockIdx.x * 256 + threadIdx.x;
    int j = id >> 12, n = id & 4095;
    int i = j & 15;
    float pos = (j < 16) ? (float)(n >> 6) : (float)(n & 63);
    float freq = exp2f(-(float)i * 0.8304820237218406f);  // 10000^(-i/16)
    float ang = pos * freq;
    ct[id] = cosf(ang);
    st[id] = sinf(ang);
}

// ------------------------------------------------------- x transpose+convert
__global__ __launch_bounds__(256) void transpose_x_kernel(
        const float* __restrict__ x, unsigned short* __restrict__ xt) {
    __shared__ unsigned short T[64 * 72];
    int t = threadIdx.x;
    int b = blockIdx.z, c0 = blockIdx.y * 64, n0 = blockIdx.x * 64;
    const float* xb = x + ((size_t)b * CDIM + c0) * NN + n0;
    int crow = t >> 2, nseg = t & 3;
#pragma unroll
    for (int g = 0; g < 4; ++g) {
        float4 f = *(const float4*)(xb + (size_t)crow * NN + nseg * 16 + g * 4);
        int nb = nseg * 16 + g * 4;
        T[(nb + 0) * 72 + crow] = bf16_1(f.x);
        T[(nb + 1) * 72 + crow] = bf16_1(f.y);
        T[(nb + 2) * 72 + crow] = bf16_1(f.z);
        T[(nb + 3) * 72 + crow] = bf16_1(f.w);
    }
    __syncthreads();
    unsigned short* xo = xt + ((size_t)b * NN + n0) * CDIM + c0;
    int nrow = t >> 2, cseg = t & 3;
    uint4 u0 = *(uint4*)(T + nrow * 72 + cseg * 16);
    uint4 u1 = *(uint4*)(T + nrow * 72 + cseg * 16 + 8);
    *(uint4*)(xo + (size_t)nrow * CDIM + cseg * 16)     = u0;
    *(uint4*)(xo + (size_t)nrow * CDIM + cseg * 16 + 8) = u1;
}

// ------------------------------------------------------- qkv MFMA GEMM
__global__ __launch_bounds__(256, 2) void qkv_mfma_kernel(
        const unsigned short* __restrict__ xt, const unsigned short* __restrict__ wq,
        unsigned short* __restrict__ qbf, unsigned short* __restrict__ kbf,
        unsigned short* __restrict__ vt,
        const float* __restrict__ ct, const float* __restrict__ st) {
    __shared__ unsigned short smem[8192];
    int t = threadIdx.x;
    int lane = t & 63, w = t >> 6;
    int qlo = lane & 15, quad = lane >> 4;
    int b = blockIdx.z, o0 = blockIdx.y * 128, n0 = blockIdx.x * 128;
    const unsigned short* xb = xt + (size_t)b * NN * CDIM;
    int row = t >> 2, seg = t & 3;
    int wn = (w & 1) * 64, wo = (w >> 1) * 64;

    f32x4 acc[4][4];
#pragma unroll
    for (int i = 0; i < 4; ++i)
#pragma unroll
        for (int j = 0; j < 4; ++j) acc[i][j] = f32x4{0.f, 0.f, 0.f, 0.f};

    for (int k0 = 0; k0 < 512; k0 += 32) {
        __syncthreads();
        load_lds16(xb + (size_t)(n0 + row) * 512 + k0 + seg * 8,        smem + t * 8);
        load_lds16(xb + (size_t)(n0 + 64 + row) * 512 + k0 + seg * 8,   smem + 2048 + t * 8);
        load_lds16(wq + (size_t)(o0 + row) * 512 + k0 + seg * 8,        smem + 4096 + t * 8);
        load_lds16(wq + (size_t)(o0 + 64 + row) * 512 + k0 + seg * 8,   smem + 6144 + t * 8);
        __syncthreads();
        U4S8 af[4], bf[4];
#pragma unroll
        for (int mt = 0; mt < 4; ++mt)
            af[mt].u = *(const uint4*)(smem + (wn + 16 * mt + qlo) * 32 + quad * 8);
#pragma unroll
        for (int nt = 0; nt < 4; ++nt)
            bf[nt].u = *(const uint4*)(smem + 4096 + (wo + 16 * nt + qlo) * 32 + quad * 8);
#pragma unroll
        for (int mt = 0; mt < 4; ++mt)
#pragma unroll
            for (int nt = 0; nt < 4; ++nt)
                acc[mt][nt] = __builtin_amdgcn_mfma_f32_16x16x32_bf16(
                    af[mt].s, bf[nt].s, acc[mt][nt], 0, 0, 0);
    }

    int og = o0 + wo;
    int s = og >> 9;
    int h = (og & 511) >> 6;
    int bh = b * HEADS + h;
    if (s < 2) {
        unsigned short* dst = (s ? kbf : qbf) + (size_t)bh * NN * HD;
#pragma unroll
        for (int mt = 0; mt < 4; ++mt) {
            int nbase = n0 + wn + 16 * mt + 4 * quad;
#pragma unroll
            for (int ntp = 0; ntp < 2; ++ntp) {
                int j = 16 * ntp + qlo;
                float4 c4 = *(const float4*)(ct + (size_t)j * NN + nbase);
                float4 s4 = *(const float4*)(st + (size_t)j * NN + nbase);
                float cc[4] = {c4.x, c4.y, c4.z, c4.w};
                float ss[4] = {s4.x, s4.y, s4.z, s4.w};
#pragma unroll
                for (int r = 0; r < 4; ++r) {
                    float x1 = acc[mt][ntp][r], x2 = acc[mt][ntp + 2][r];
                    size_t base = (size_t)(nbase + r) * HD;
                    dst[base + j]      = bf16_1(x1 * cc[r] - x2 * ss[r]);
                    dst[base + j + 32] = bf16_1(x1 * ss[r] + x2 * cc[r]);
                }
            }
        }
    } else {
        unsigned short* dst = vt + (size_t)bh * HD * NN;
#pragma unroll
        for (int mt = 0; mt < 4; ++mt)
#pragma unroll
            for (int nt = 0; nt < 4; ++nt) {
                int d = 16 * nt + qlo;
                int n = n0 + wn + 16 * mt + 4 * quad;
                uint2 u;
                u.x = pk(acc[mt][nt][0], acc[mt][nt][1]);
                u.y = pk(acc[mt][nt][2], acc[mt][nt][3]);
                *(uint2*)(dst + (size_t)d * NN + n) = u;
            }
    }
}

// ------------------------------------------------------- attention (16x16 MFMA)
// R4 structure: wave owns 64 queries (4 tiles), block = 4 waves = 256 queries.
// Sᵀ=K·Qᵀ; P stays in registers (C-layout == A-layout under the key-perm
// applied to V at LDS staging). exp2 softmax, VALU l.
// + XCD swizzle (16 q-blocks of one bh per XCD -> K/V L2-resident)
// + 128-key staging per barrier, two 64-key compute sub-chunks.
// LDS: K 128x144B @0 (18432), V(perm) 64x272B @18432 (17408) = 35840 B.
__global__ __launch_bounds__(256, 2) void attn_kernel(
        const unsigned short* __restrict__ qbf, const unsigned short* __restrict__ kbf,
        const unsigned short* __restrict__ vt, unsigned short* __restrict__ aot) {
    __shared__ unsigned char smem[35840];
    const int VB = 18432;
    int t = threadIdx.x;
    int lane = t & 63, w = t >> 6;
    int qlo = lane & 15, quad = lane >> 4;
    int L = blockIdx.x;                       // 0..511
    int bh = (L & 7) + 8 * (L >> 7);          // 16 q-blocks of a bh share one XCD
    int qb = (L >> 3) & 15;
    int bb = bh >> 3, hh = bh & 7;
    int n0w = qb * 256 + w * 64;

    // Q B-frags [nt][kt]: Q[query=16nt+qlo][hd=32kt+8quad+j]
    U4S8 qf[4][2];
    const unsigned short* qg = qbf + ((size_t)bh * NN + n0w) * HD;
#pragma unroll
    for (int nt = 0; nt < 4; ++nt)
#pragma unroll
        for (int kt = 0; kt < 2; ++kt)
            qf[nt][kt].u = *(const uint4*)(qg + (size_t)(16 * nt + qlo) * 64 + 32 * kt + 8 * quad);

    f32x4 O[4][4];
#pragma unroll
    for (int mt = 0; mt < 4; ++mt)
#pragma unroll
        for (int nt = 0; nt < 4; ++nt) O[mt][nt] = f32x4{0.f, 0.f, 0.f, 0.f};
    float lx[4] = {0.f, 0.f, 0.f, 0.f};
    float ly[4] = {0.f, 0.f, 0.f, 0.f};

    const uint4* kg = (const uint4*)kbf + (size_t)bh * NN * 8;     // K row = 8 uint4
    const uint4* vg = (const uint4*)vt  + (size_t)bh * 64 * 512;   // V row = 512 uint4

    int kof[4], vof[4];
    const uint4* kgp[4]; const uint4* vgp[4];
    uint4 kr[4], vr[4];
#pragma unroll
    for (int i = 0; i < 4; ++i) {
        int idx = t + 256 * i;                // 0..1023
        kof[i] = (idx >> 3) * 144 + (idx & 7) * 16;
        kgp[i] = kg + (size_t)(idx >> 3) * 8 + (idx & 7);
        int hd = idx >> 4, u = idx & 15;
        int sc = u >> 3, s8 = u & 7;
        vof[i] = VB + hd * 272 + sc * 128
               + (s8 >> 2) * 64 + (s8 & 1) * 32 + ((s8 >> 1) & 1) * 8;   // key-perm
        vgp[i] = vg + (size_t)hd * 512 + u;
        kr[i] = kgp[i][0];
        vr[i] = vgp[i][0];
    }

    for (int it = 0; it < 32; ++it) {
        __syncthreads();
#pragma unroll
        for (int i = 0; i < 4; ++i)
            *(uint4*)(smem + kof[i]) = kr[i];
#pragma unroll
        for (int i = 0; i < 4; ++i) {
            *(uint2*)(smem + vof[i])      = make_uint2(vr[i].x, vr[i].y);
            *(uint2*)(smem + vof[i] + 16) = make_uint2(vr[i].z, vr[i].w);
        }
        __syncthreads();
        if (it + 1 < 32) {
#pragma unroll
            for (int i = 0; i < 4; ++i) {
                kr[i] = kgp[i][(size_t)(it + 1) * 1024];
                vr[i] = vgp[i][(size_t)(it + 1) * 16];
            }
        }

#pragma unroll
        for (int sc2 = 0; sc2 < 2; ++sc2) {
            // ---- Sᵀ = K · Qᵀ : S[mt][nt], key=16mt+4quad+r (sub-chunk), query=qlo
            f32x4 S[4][4];
#pragma unroll
            for (int mt = 0; mt < 4; ++mt)
#pragma unroll
                for (int nt = 0; nt < 4; ++nt) S[mt][nt] = f32x4{0.f, 0.f, 0.f, 0.f};
#pragma unroll
            for (int kt = 0; kt < 2; ++kt) {
                U4S8 ka[4];
#pragma unroll
                for (int mt = 0; mt < 4; ++mt)
                    ka[mt].u = *(const uint4*)(smem + (64 * sc2 + 16 * mt + qlo) * 144
                                               + kt * 64 + quad * 16);
#pragma unroll
                for (int nt = 0; nt < 4; ++nt)
#pragma unroll
                    for (int mt = 0; mt < 4; ++mt)
                        S[mt][nt] = __builtin_amdgcn_mfma_f32_16x16x32_bf16(
                            ka[mt].s, qf[nt][kt].s, S[mt][nt], 0, 0, 0);
            }

            // ---- exp2 + in-register bf16 P (A-layout under key-perm)
            uint2 pd[4][4];
#pragma unroll
            for (int nt = 0; nt < 4; ++nt)
#pragma unroll
                for (int mt = 0; mt < 4; ++mt) {
                    f32x4 s4 = S[mt][nt];
                    float p0 = __builtin_amdgcn_exp2f(s4[0]);
                    float p1 = __builtin_amdgcn_exp2f(s4[1]);
                    float p2 = __builtin_amdgcn_exp2f(s4[2]);
                    float p3 = __builtin_amdgcn_exp2f(s4[3]);
                    lx[nt] += p0 + p2;
                    ly[nt] += p1 + p3;
                    pd[nt][mt] = make_uint2(pkru(p0, p1), pkru(p2, p3));
                }

            // ---- O += P · V
#pragma unroll
            for (int kt = 0; kt < 2; ++kt) {
                U4S8 pa[4];
#pragma unroll
                for (int mtP = 0; mtP < 4; ++mtP)
                    pa[mtP].u = make_uint4(pd[mtP][2 * kt].x, pd[mtP][2 * kt].y,
                                           pd[mtP][2 * kt + 1].x, pd[mtP][2 * kt + 1].y);
#pragma unroll
                for (int nt = 0; nt < 4; ++nt) {
                    U4S8 vb;
                    vb.u = *(const uint4*)(smem + VB + (16 * nt + qlo) * 272
                                           + sc2 * 128 + kt * 64 + quad * 16);
#pragma unroll
                    for (int mtP = 0; mtP < 4; ++mtP)
                        O[mtP][nt] = __builtin_amdgcn_mfma_f32_16x16x32_bf16(
                            pa[mtP].s, vb.s, O[mtP][nt], 0, 0, 0);
                }
            }
        }
    }

    // ---- finalize
    float linv[4];
#pragma unroll
    for (int nt = 0; nt < 4; ++nt) {
        float l = lx[nt] + ly[nt];
        l += __shfl_xor(l, 16, 64);
        l += __shfl_xor(l, 32, 64);
        linv[nt] = 1.0f / l;
    }
    __syncthreads();                          // staging LDS now reusable
    unsigned short* Tw = (unsigned short*)(smem + w * 4608);  // 16 x 72 elems
    unsigned short* aob = aot + (size_t)bb * NN * CDIM + hh * 64;
#pragma unroll
    for (int mt = 0; mt < 4; ++mt) {
        float iv[4];
#pragma unroll
        for (int r = 0; r < 4; ++r) iv[r] = __shfl(linv[mt], 4 * quad + r, 64);
#pragma unroll
        for (int nt = 0; nt < 4; ++nt)
#pragma unroll
            for (int r = 0; r < 4; ++r)
                Tw[(4 * quad + r) * 72 + 16 * nt + qlo] = bf16_1(O[mt][nt][r] * iv[r]);
        int row = lane >> 2, cseg = lane & 3;
        uint4 u0 = *(uint4*)(Tw + row * 72 + cseg * 16);
        uint4 u1 = *(uint4*)(Tw + row * 72 + cseg * 16 + 8);
        unsigned short* arow = aob + (size_t)(n0w + 16 * mt + row) * CDIM + cseg * 16;
        *(uint4*)(arow)     = u0;
        *(uint4*)(arow + 8) = u1;
    }
}

// ------------------------------------------------------- proj MFMA GEMM
__global__ __launch_bounds__(256, 2) void proj_mfma_kernel(
        const unsigned short* __restrict__ aot, const unsigned short* __restrict__ wp,
        float* __restrict__ out) {
    __shared__ unsigned short smem[8192];
    int t = threadIdx.x;
    int lane = t & 63, w = t >> 6;
    int qlo = lane & 15, quad = lane >> 4;
    int b = blockIdx.z, o0 = blockIdx.y * 128, n0 = blockIdx.x * 128;
    const unsigned short* ab = aot + (size_t)b * NN * CDIM;
    int row = t >> 2, seg = t & 3;
    int wn = (w & 1) * 64, wo = (w >> 1) * 64;

    f32x4 acc[4][4];
#pragma unroll
    for (int i = 0; i < 4; ++i)
#pragma unroll
        for (int j = 0; j < 4; ++j) acc[i][j] = f32x4{0.f, 0.f, 0.f, 0.f};

    for (int k0 = 0; k0 < 512; k0 += 32) {
        __syncthreads();
        load_lds16(ab + (size_t)(n0 + row) * 512 + k0 + seg * 8,        smem + t * 8);
        load_lds16(ab + (size_t)(n0 + 64 + row) * 512 + k0 + seg * 8,   smem + 2048 + t * 8);
        load_lds16(wp + (size_t)(o0 + row) * 512 + k0 + seg * 8,        smem + 4096 + t * 8);
        load_lds16(wp + (size_t)(o0 + 64 + row) * 512 + k0 + seg * 8,   smem + 6144 + t * 8);
        __syncthreads();
        U4S8 af[4], bf[4];
#pragma unroll
        for (int mt = 0; mt < 4; ++mt)
            af[mt].u = *(const uint4*)(smem + (wn + 16 * mt + qlo) * 32 + quad * 8);
#pragma unroll
        for (int nt = 0; nt < 4; ++nt)
            bf[nt].u = *(const uint4*)(smem + 4096 + (wo + 16 * nt + qlo) * 32 + quad * 8);
#pragma unroll
        for (int mt = 0; mt < 4; ++mt)
#pragma unroll
            for (int nt = 0; nt < 4; ++nt)
                acc[mt][nt] = __builtin_amdgcn_mfma_f32_16x16x32_bf16(
                    af[mt].s, bf[nt].s, acc[mt][nt], 0, 0, 0);
    }

    float* ob = out + (size_t)b * CDIM * NN;
#pragma unroll
    for (int mt = 0; mt < 4; ++mt)
#pragma unroll
        for (int nt = 0; nt < 4; ++nt) {
            int o = o0 + wo + 16 * nt + qlo;
            int n = n0 + wn + 16 * mt + 4 * quad;
            *(float4*)(ob + (size_t)o * NN + n) = *(float4*)&acc[mt][nt];
        }
}

// ------------------------------------------------------- launch
extern "C" void kernel_launch(void* const* d_in, const int* in_sizes, int n_in,
                              void* d_out, int out_size, void* d_ws, size_t ws_size,
                              hipStream_t stream) {
    const float* x      = (const float*)d_in[0];
    const float* w_qkv  = (const float*)d_in[1];
    const float* w_proj = (const float*)d_in[2];
    float* out = (float*)d_out;
    unsigned short* ws = (unsigned short*)d_ws;

    unsigned short* xt  = ws;                  // bf16 [b][n][c]
    unsigned short* qbf = xt  + QSZ;           // bf16 [bh][n][d]
    unsigned short* kbf = qbf + QSZ;           // bf16 [bh][n][d]
    unsigned short* vt  = kbf + QSZ;           // bf16 [bh][d][n]
    unsigned short* aot = vt  + QSZ;           // bf16 [b][n][c]
    unsigned short* wqb = aot + QSZ;           // bf16 [1536][512]
    unsigned short* wpb = wqb + 786432;        // bf16 [512][512]
    float* ct = (float*)(wpb + 262144);        // [32][4096]
    float* st = ct + 32 * 4096;

    conv_w_kernel<<<512, 256, 0, stream>>>(w_qkv, w_proj, wqb, wpb);
    rope_table_kernel<<<512, 256, 0, stream>>>(ct, st);
    transpose_x_kernel<<<dim3(64, 8, B_), 256, 0, stream>>>(x, xt);
    qkv_mfma_kernel<<<dim3(32, 12, B_), 256, 0, stream>>>(xt, wqb, qbf, kbf, vt, ct, st);
    attn_kernel<<<512, 256, 0, stream>>>(qbf, kbf, vt, aot);
    proj_mfma_kernel<<<dim3(32, 4, B_), 256, 0, stream>>>(aot, wpb, out);
}